// Round 3
// baseline (2273.104 us; speedup 1.0000x reference)
//
#include <hip/hip_runtime.h>

#define NQT 16384
#define NAT 512
#define EAQ 131072
#define EQQ 262144

typedef short short8 __attribute__((ext_vector_type(8)));
typedef short short4v __attribute__((ext_vector_type(4)));
typedef float float4v __attribute__((ext_vector_type(4)));

__device__ __forceinline__ float silu_f(float x){ return x / (1.f + __expf(-x)); }

__device__ __forceinline__ short f2bf(float f){
  union { float f; unsigned u; } v; v.f = f;
  unsigned r = v.u + 0x7fff + ((v.u >> 16) & 1);
  return (short)(r >> 16);
}

// ---------------- counting sort by tgt ----------------
__global__ __launch_bounds__(256) void k_hist(
    const int* __restrict__ etgt, int* __restrict__ hist, int E)
{
  int i = blockIdx.x*256 + threadIdx.x;
  if (i < E) atomicAdd(&hist[etgt[i]], 1);
}

__global__ __launch_bounds__(256) void k_scan(int* __restrict__ hist)
{ // 16384 bins -> exclusive offsets, single block
  __shared__ int part[256];
  int t = threadIdx.x;
  int base = t * 64;
  int s = 0;
  for (int i = 0; i < 64; i++) s += hist[base + i];
  part[t] = s;
  __syncthreads();
  for (int off = 1; off < 256; off <<= 1){
    int v = (t >= off) ? part[t - off] : 0;
    __syncthreads();
    part[t] += v;
    __syncthreads();
  }
  int run = (t == 0) ? 0 : part[t-1];
  for (int i = 0; i < 64; i++){
    int h = hist[base + i];
    hist[base + i] = run;
    run += h;
  }
}

__global__ __launch_bounds__(256) void k_place(
    const int* __restrict__ etgt, int* __restrict__ cursor,
    int* __restrict__ perm, int E)
{
  int i = blockIdx.x*256 + threadIdx.x;
  if (i < E){
    int pos = atomicAdd(&cursor[etgt[i]], 1);
    perm[pos] = i;
  }
}

// ---------------- weight packer: (rows,cols) f32 -> MFMA B-frag bf16 ----------------
__global__ __launch_bounds__(256) void k_pack(
    const float* __restrict__ W, short* __restrict__ out,
    int rows, int cols, int ksteps, int ntiles, int total, int remap256)
{
  int idx = blockIdx.x * 256 + threadIdx.x;
  if (idx >= total) return;
  int l8   = idx & 7;
  int lane = (idx >> 3) & 63;
  int kk   = (idx >> 9) % ksteps;
  int nt   = ((idx >> 9) / ksteps) % ntiles;
  int j    = idx / (512 * ksteps * ntiles);
  int k = kk*32 + (lane >> 4)*8 + l8;
  if (remap256 && k >= 256) k += 1;          // skip sq row (f32 epilogue)
  int n = nt*16 + (lane & 15);
  out[idx] = f2bf(W[(size_t)j*rows*cols + (size_t)k*cols + n]);
}

// ---------------- h_atom ----------------
__global__ __launch_bounds__(128) void k_hatom(
    const float* __restrict__ feat, const float* __restrict__ W,
    const float* __restrict__ b, float* __restrict__ out)
{
  __shared__ float sf[256];
  int n = blockIdx.x, t = threadIdx.x;
  sf[t]       = feat[n*256 + t];
  sf[t + 128] = feat[n*256 + 128 + t];
  __syncthreads();
  float acc = b[t];
  for (int k = 0; k < 256; k++) acc += sf[k] * W[k*128 + t];
  out[n*128 + t] = acc;
}

// ---------------- t_emb ----------------
__global__ __launch_bounds__(256) void k_temb(
    const float* __restrict__ tq,
    const float* __restrict__ W1, const float* __restrict__ b1,
    const float* __restrict__ W2, const float* __restrict__ b2,
    float* __restrict__ temb)
{
  __shared__ float emb[128*8];
  __shared__ float hid[512*8];
  int t = threadIdx.x, n0 = blockIdx.x * 8;
  #pragma unroll
  for (int i = 0; i < 4; i++){
    int idx = t + 256*i;
    int k = idx >> 3, n = idx & 7;
    float tv = tq[n0 + n];
    int h = k & 63;
    float freq = __expf(-9.210340371976184f * (float)h * (1.f/63.f));
    float a = tv * freq;
    emb[idx] = (k < 64) ? __sinf(a) : __cosf(a);
  }
  __syncthreads();
  float acc[16];
  #pragma unroll
  for (int i = 0; i < 16; i++) acc[i] = 0.f;
  const float4* ev = (const float4*)emb;
  for (int k = 0; k < 128; k++){
    float wa = W1[k*512 + t];
    float wb = W1[k*512 + t + 256];
    float4 e0 = ev[k*2], e1 = ev[k*2 + 1];
    acc[0]+=wa*e0.x; acc[1]+=wa*e0.y; acc[2]+=wa*e0.z; acc[3]+=wa*e0.w;
    acc[4]+=wa*e1.x; acc[5]+=wa*e1.y; acc[6]+=wa*e1.z; acc[7]+=wa*e1.w;
    acc[8]+=wb*e0.x; acc[9]+=wb*e0.y; acc[10]+=wb*e0.z; acc[11]+=wb*e0.w;
    acc[12]+=wb*e1.x; acc[13]+=wb*e1.y; acc[14]+=wb*e1.z; acc[15]+=wb*e1.w;
  }
  float ba = b1[t], bb = b1[t + 256];
  #pragma unroll
  for (int n = 0; n < 8; n++){
    hid[t*8 + n]        = silu_f(acc[n] + ba);
    hid[(t+256)*8 + n]  = silu_f(acc[8+n] + bb);
  }
  __syncthreads();
  float a2[4] = {0.f,0.f,0.f,0.f};
  int c = t & 127, nh = t >> 7;
  const float4* hv = (const float4*)hid;
  for (int k = 0; k < 512; k++){
    float w = W2[k*128 + c];
    float4 h4 = hv[k*2 + nh];
    a2[0]+=w*h4.x; a2[1]+=w*h4.y; a2[2]+=w*h4.z; a2[3]+=w*h4.w;
  }
  float bc = b2[c];
  #pragma unroll
  for (int i = 0; i < 4; i++)
    temb[(size_t)(n0 + nh*4 + i)*128 + c] = a2[i] + bc;
}

// ---------------- h init ----------------
__global__ __launch_bounds__(128) void k_hinit(
    const float* __restrict__ x_t, const float* __restrict__ atom_pos,
    const float* __restrict__ W1, const float* __restrict__ b1,
    const float* __restrict__ W2, const float* __restrict__ b2,
    float* __restrict__ h)
{
  __shared__ float sh[128];
  __shared__ float sld;
  int n = blockIdx.x, t = threadIdx.x;
  float qx = x_t[n*3], qy = x_t[n*3+1], qz = x_t[n*3+2];
  float part = 0.f;
  if (t < 64){
    int a = (n >> 11)*64 + t;
    float dx = qx - atom_pos[a*3];
    float dy = qy - atom_pos[a*3+1];
    float dz = qz - atom_pos[a*3+2];
    part = dx*dx + dy*dy + dz*dz;
  }
  #pragma unroll
  for (int off = 32; off; off >>= 1) part += __shfl_down(part, off);
  if (t == 0) sld = log1pf(sqrtf(part * (1.f/64.f)) * 0.125f);
  __syncthreads();
  float ld = sld;
  sh[t] = silu_f(ld * W1[t] + b1[t]);
  __syncthreads();
  float acc = b2[t];
  for (int k = 0; k < 128; k++) acc += sh[k] * W2[k*128 + t];
  h[(size_t)n*128 + t] = acc;
}

// ---------------- EGNN edge kernel (tgt-sorted, segmented agg) ----------------
__global__ __launch_bounds__(256) void k_edge(
    const float* __restrict__ h_src, const float* __restrict__ h_tgt,
    const float* __restrict__ pos_src, const float* __restrict__ pos_tgt,
    const float* __restrict__ temb,
    const int* __restrict__ esrc, const int* __restrict__ etgt,
    const int* __restrict__ perm,
    const short* __restrict__ W1p, const float* __restrict__ w1full, const float* __restrict__ b1,
    const short* __restrict__ W2p, const float* __restrict__ b2,
    const short* __restrict__ W3p, const float* __restrict__ b3,
    const float* __restrict__ W4,  const float* __restrict__ b4,
    float* __restrict__ agg, float* __restrict__ vel)
{
  __shared__ __align__(16) short A1[32*392];   // mi bf16 [e][384] stride 392
  __shared__ __align__(16) short A2[32*264];   // hid bf16 [e][256] stride 264
  __shared__ float sq_s[32];
  __shared__ float rel_s[32*3];
  __shared__ int   tgt_s[32];
  short* A3   = A1;                     // bf16 msg [e][128] stride 136, bytes [0,8704)
  float* h3   = (float*)(A1 + 4608);    // f32 [e][64] stride 68, bytes [9216,17920)
  float* msgf = (float*)A2;             // f32 msg [e][128] stride 132 (aliases dead hid)

  int t = threadIdx.x;
  int e0 = blockIdx.x * 32;

  // ---- stage: gather via perm + cast bf16 (8 threads / edge) ----
  {
    int e = t >> 3, l = t & 7;
    int pe = perm[e0 + e];
    int src = esrc[pe], tgt = etgt[pe];
    const float4* hs = (const float4*)(h_src + (size_t)src*128);
    const float4* ht = (const float4*)(h_tgt + (size_t)tgt*128);
    const float4* te = (const float4*)(temb  + (size_t)tgt*128);
    short* row = A1 + e*392;
    #pragma unroll
    for (int i = 0; i < 4; i++){
      int k4 = l + 8*i;
      float4 a = hs[k4], b = ht[k4], c = te[k4];
      short4v s;
      s.x=f2bf(a.x); s.y=f2bf(a.y); s.z=f2bf(a.z); s.w=f2bf(a.w);
      *(short4v*)(row + k4*4) = s;
      s.x=f2bf(b.x); s.y=f2bf(b.y); s.z=f2bf(b.z); s.w=f2bf(b.w);
      *(short4v*)(row + 128 + k4*4) = s;
      s.x=f2bf(c.x); s.y=f2bf(c.y); s.z=f2bf(c.z); s.w=f2bf(c.w);
      *(short4v*)(row + 256 + k4*4) = s;
    }
    if (l == 0){
      float rx = pos_tgt[tgt*3+0] - pos_src[src*3+0];
      float ry = pos_tgt[tgt*3+1] - pos_src[src*3+1];
      float rz = pos_tgt[tgt*3+2] - pos_src[src*3+2];
      sq_s[e] = rx*rx + ry*ry + rz*rz;
      rel_s[e*3+0]=rx; rel_s[e*3+1]=ry; rel_s[e*3+2]=rz;
      tgt_s[e] = tgt;
    }
  }
  __syncthreads();

  int lane = t & 63, w = t >> 6;
  int mrow = lane & 15, quad = lane >> 4;

  // ---- GEMM1: (32x384)@(384x256) [+ sq rank-1 f32] + silu -> A2 ----
  for (int nti = 0; nti < 4; nti++){
    int nt = w*4 + nti;
    #pragma unroll
    for (int mt = 0; mt < 2; mt++){
      float4v acc = {0.f,0.f,0.f,0.f};
      const short8* Ab = (const short8*)(A1 + (mt*16 + mrow)*392 + quad*8);
      const short8* Bb = (const short8*)(W1p + (size_t)nt*12*512 + lane*8);
      #pragma unroll
      for (int kk = 0; kk < 12; kk++)
        acc = __builtin_amdgcn_mfma_f32_16x16x32_bf16(Ab[kk*4], Bb[kk*64], acc, 0, 0, 0);
      int n = nt*16 + mrow;
      float w1sq = w1full[256*256 + n];
      float b1n  = b1[n];
      #pragma unroll
      for (int r = 0; r < 4; r++){
        int e = mt*16 + quad*4 + r;
        float v = acc[r] + b1n + sq_s[e]*w1sq;
        A2[e*264 + n] = f2bf(silu_f(v));
      }
    }
  }
  __syncthreads();

  // ---- GEMM2 MFMAs: (32x256)@(256x128), keep accs in regs ----
  float4v acc2[2][2];
  #pragma unroll
  for (int nti = 0; nti < 2; nti++){
    int nt = w*2 + nti;
    #pragma unroll
    for (int mt = 0; mt < 2; mt++){
      float4v acc = {0.f,0.f,0.f,0.f};
      const short8* Ab = (const short8*)(A2 + (mt*16 + mrow)*264 + quad*8);
      const short8* Bb = (const short8*)(W2p + (size_t)nt*8*512 + lane*8);
      #pragma unroll
      for (int kk = 0; kk < 8; kk++)
        acc = __builtin_amdgcn_mfma_f32_16x16x32_bf16(Ab[kk*4], Bb[kk*64], acc, 0, 0, 0);
      acc2[nti][mt] = acc;
    }
  }
  __syncthreads();   // all reads of A2 (hid) done — safe to alias as msgf

  // ---- GEMM2 epilogue: silu -> msgf (f32) + A3 (bf16) ----
  #pragma unroll
  for (int nti = 0; nti < 2; nti++){
    int nt = w*2 + nti;
    int n = nt*16 + mrow;
    float b2n = b2[n];
    #pragma unroll
    for (int mt = 0; mt < 2; mt++){
      #pragma unroll
      for (int r = 0; r < 4; r++){
        int e = mt*16 + quad*4 + r;
        float v = silu_f(acc2[nti][mt][r] + b2n);
        msgf[e*132 + n] = v;
        A3[e*136 + n]   = f2bf(v);
      }
    }
  }
  __syncthreads();

  // ---- segmented agg reduction: one atomic per distinct tgt per col ----
  {
    int c = t & 127, hh = t >> 7;
    int eb = hh*16;
    float run = 0.f;
    int cur = tgt_s[eb];
    for (int e = eb; e < eb + 16; e++){
      int tg = tgt_s[e];
      if (tg != cur){
        atomicAdd(&agg[(size_t)cur*128 + c], run);
        run = 0.f; cur = tg;
      }
      run += msgf[e*132 + c];
    }
    atomicAdd(&agg[(size_t)cur*128 + c], run);
  }

  // ---- GEMM3: (32x128)@(128x64) + silu -> h3 (f32, in A1 tail) ----
  {
    int nt = w;
    #pragma unroll
    for (int mt = 0; mt < 2; mt++){
      float4v acc = {0.f,0.f,0.f,0.f};
      const short8* Ab = (const short8*)(A3 + (mt*16 + mrow)*136 + quad*8);
      const short8* Bb = (const short8*)(W3p + (size_t)nt*4*512 + lane*8);
      #pragma unroll
      for (int kk = 0; kk < 4; kk++)
        acc = __builtin_amdgcn_mfma_f32_16x16x32_bf16(Ab[kk*4], Bb[kk*64], acc, 0, 0, 0);
      int n = nt*16 + mrow;
      float b3n = b3[n];
      #pragma unroll
      for (int r = 0; r < 4; r++){
        int e = mt*16 + quad*4 + r;
        h3[e*68 + n] = silu_f(acc[r] + b3n);
      }
    }
  }
  __syncthreads();

  // ---- GEMM4 (f32 dot-64) + tanh + vel scatter ----
  {
    int e = t >> 3, l = t & 7;
    float p = 0.f;
    #pragma unroll
    for (int i = 0; i < 8; i++){
      int k = l + 8*i;
      p += h3[e*68 + k] * W4[k];
    }
    p += __shfl_xor(p, 1);
    p += __shfl_xor(p, 2);
    p += __shfl_xor(p, 4);
    if (l == 0){
      float wv = tanhf(p + b4[0]);
      int tg = tgt_s[e];
      atomicAdd(&vel[tg*3+0], wv*rel_s[e*3+0]);
      atomicAdd(&vel[tg*3+1], wv*rel_s[e*3+1]);
      atomicAdd(&vel[tg*3+2], wv*rel_s[e*3+2]);
    }
  }
}

// ---------------- node update ----------------
__global__ __launch_bounds__(256) void k_node(
    const float* __restrict__ h, const float* __restrict__ agg,
    const float* __restrict__ W1, const float* __restrict__ b1,
    const float* __restrict__ W2, const float* __restrict__ b2,
    const float* __restrict__ g, const float* __restrict__ bb_,
    float* __restrict__ h_out)
{
  __shared__ float u[256*16];
  __shared__ float hid[128*16];
  __shared__ float r[16*128];
  int t = threadIdx.x;
  int n0 = blockIdx.x * 16;
  {
    int l = t & 15, n = t >> 4;
    const float* hr = h   + (size_t)(n0+n)*128;
    const float* ar = agg + (size_t)(n0+n)*128;
    #pragma unroll
    for (int i = 0; i < 8; i++){
      int k = l + 16*i;
      u[k*16 + n]         = hr[k];
      u[(128 + k)*16 + n] = ar[k];
    }
  }
  __syncthreads();
  int c = t & 63, q = t >> 6;
  {
    float acc[8];
    #pragma unroll
    for (int i = 0; i < 8; i++) acc[i] = 0.f;
    const float4* uv = (const float4*)u;
    for (int k = 0; k < 256; k++){
      float wa = W1[k*128 + c];
      float wb = W1[k*128 + c + 64];
      float4 u4 = uv[k*4 + q];
      acc[0]+=wa*u4.x; acc[1]+=wa*u4.y; acc[2]+=wa*u4.z; acc[3]+=wa*u4.w;
      acc[4]+=wb*u4.x; acc[5]+=wb*u4.y; acc[6]+=wb*u4.z; acc[7]+=wb*u4.w;
    }
    float ba = b1[c], bv = b1[c + 64];
    #pragma unroll
    for (int i = 0; i < 4; i++){
      int n = q*4 + i;
      hid[c*16 + n]        = silu_f(acc[i] + ba);
      hid[(c+64)*16 + n]   = silu_f(acc[4+i] + bv);
    }
  }
  __syncthreads();
  {
    float acc[8];
    #pragma unroll
    for (int i = 0; i < 8; i++) acc[i] = 0.f;
    const float4* hv = (const float4*)hid;
    for (int k = 0; k < 128; k++){
      float wa = W2[k*128 + c];
      float wb = W2[k*128 + c + 64];
      float4 h4 = hv[k*4 + q];
      acc[0]+=wa*h4.x; acc[1]+=wa*h4.y; acc[2]+=wa*h4.z; acc[3]+=wa*h4.w;
      acc[4]+=wb*h4.x; acc[5]+=wb*h4.y; acc[6]+=wb*h4.z; acc[7]+=wb*h4.w;
    }
    float ba = b2[c], bv = b2[c + 64];
    #pragma unroll
    for (int i = 0; i < 4; i++){
      int n = q*4 + i;
      r[n*128 + c]      = h[(size_t)(n0+n)*128 + c]      + acc[i]   + ba;
      r[n*128 + c + 64] = h[(size_t)(n0+n)*128 + c + 64] + acc[4+i] + bv;
    }
  }
  __syncthreads();
  {
    int lane = t & 63, wid = t >> 6;
    #pragma unroll
    for (int nn = 0; nn < 4; nn++){
      int n = wid*4 + nn;
      float a = r[n*128 + lane], b2v = r[n*128 + lane + 64];
      float s = a + b2v, ss = a*a + b2v*b2v;
      #pragma unroll
      for (int off = 1; off < 64; off <<= 1){
        s  += __shfl_xor(s, off);
        ss += __shfl_xor(ss, off);
      }
      float mean = s * (1.f/128.f);
      float var  = ss * (1.f/128.f) - mean*mean;
      float rstd = rsqrtf(var + 1e-5f);
      float* ho = h_out + (size_t)(n0+n)*128;
      ho[lane]      = (a   - mean)*rstd*g[lane]      + bb_[lane];
      ho[lane + 64] = (b2v - mean)*rstd*g[lane + 64] + bb_[lane + 64];
    }
  }
}

// ---------------- output ----------------
__global__ __launch_bounds__(128) void k_out(
    const float* __restrict__ h, const float* __restrict__ vel,
    const float* __restrict__ W1, const float* __restrict__ b1,
    const float* __restrict__ W2, const float* __restrict__ b2,
    float* __restrict__ out)
{
  __shared__ float sh[128];
  __shared__ float spart[2];
  int n = blockIdx.x, t = threadIdx.x;
  sh[t] = h[(size_t)n*128 + t];
  __syncthreads();
  float acc = b1[t];
  for (int k = 0; k < 128; k++) acc += sh[k] * W1[k*128 + t];
  float p = silu_f(acc) * W2[t];
  #pragma unroll
  for (int off = 32; off; off >>= 1) p += __shfl_down(p, off);
  if ((t & 63) == 0) spart[t >> 6] = p;
  __syncthreads();
  if (t < 3){
    float scale = spart[0] + spart[1] + b2[0];
    out[n*3 + t] = vel[n*3 + t] * scale;
  }
}

extern "C" void kernel_launch(void* const* d_in, const int* in_sizes, int n_in,
                              void* d_out, int out_size, void* d_ws, size_t ws_size,
                              hipStream_t stream)
{
  const float* x_t       = (const float*)d_in[0];
  const float* t_query   = (const float*)d_in[1];
  const float* atom_pos  = (const float*)d_in[2];
  const float* atom_feat = (const float*)d_in[3];
  const int*   e_aq_s = (const int*)d_in[4];
  const int*   e_aq_t = (const int*)d_in[5];
  const int*   e_qq_s = (const int*)d_in[6];
  const int*   e_qq_t = (const int*)d_in[7];
  const float* apW  = (const float*)d_in[8];
  const float* apb  = (const float*)d_in[9];
  const float* tW1  = (const float*)d_in[10];
  const float* tb1  = (const float*)d_in[11];
  const float* tW2  = (const float*)d_in[12];
  const float* tb2  = (const float*)d_in[13];
  const float* qiW1 = (const float*)d_in[14];
  const float* qib1 = (const float*)d_in[15];
  const float* qiW2 = (const float*)d_in[16];
  const float* qib2 = (const float*)d_in[17];
  const float* mW1  = (const float*)d_in[18];
  const float* mb1  = (const float*)d_in[19];
  const float* mW2  = (const float*)d_in[20];
  const float* mb2  = (const float*)d_in[21];
  const float* cW1  = (const float*)d_in[22];
  const float* cb1  = (const float*)d_in[23];
  const float* cW2  = (const float*)d_in[24];
  const float* cb2  = (const float*)d_in[25];
  const float* nW1  = (const float*)d_in[26];
  const float* nb1  = (const float*)d_in[27];
  const float* nW2  = (const float*)d_in[28];
  const float* nb2  = (const float*)d_in[29];
  const float* lng  = (const float*)d_in[30];
  const float* lnb  = (const float*)d_in[31];
  const float* voW1 = (const float*)d_in[32];
  const float* vob1 = (const float*)d_in[33];
  const float* voW2 = (const float*)d_in[34];
  const float* vob2 = (const float*)d_in[35];
  float* out = (float*)d_out;

  float* ws     = (float*)d_ws;
  float* h_atom = ws;                       // 512*128
  float* temb   = h_atom + 65536;           // NQT*128
  float* hA     = temb + 2097152;
  float* hB     = hA + 2097152;
  float* agg    = hB + 2097152;
  float* vel    = agg + 2097152;            // NQT*3
  short* W1p    = (short*)(vel + 49152);    // 8*98304 shorts
  short* W2p    = W1p + 8*98304;            // 8*32768
  short* W3p    = W2p + 8*32768;            // 8*8192
  int*   hist_a = (int*)(W3p + 8*8192);     // 16384
  int*   hist_q = hist_a + 16384;           // 16384
  int*   perm_a = hist_q + 16384;           // EAQ
  int*   perm_q = perm_a + EAQ;             // EQQ

  // ---- edge sort by tgt (both sets) ----
  hipMemsetAsync(hist_a, 0, 16384*sizeof(int), stream);
  hipMemsetAsync(hist_q, 0, 16384*sizeof(int), stream);
  k_hist<<<EAQ/256, 256, 0, stream>>>(e_aq_t, hist_a, EAQ);
  k_hist<<<EQQ/256, 256, 0, stream>>>(e_qq_t, hist_q, EQQ);
  k_scan<<<1, 256, 0, stream>>>(hist_a);
  k_scan<<<1, 256, 0, stream>>>(hist_q);
  k_place<<<EAQ/256, 256, 0, stream>>>(e_aq_t, hist_a, perm_a, EAQ);
  k_place<<<EQQ/256, 256, 0, stream>>>(e_qq_t, hist_q, perm_q, EQQ);

  // ---- weight packing ----
  {
    int t1 = 8*16*12*512;
    k_pack<<<(t1+255)/256, 256, 0, stream>>>(mW1, W1p, 385, 256, 12, 16, t1, 1);
    int t2 = 8*8*8*512;
    k_pack<<<(t2+255)/256, 256, 0, stream>>>(mW2, W2p, 256, 128, 8, 8, t2, 0);
    int t3 = 8*4*4*512;
    k_pack<<<(t3+255)/256, 256, 0, stream>>>(cW1, W3p, 128, 64, 4, 4, t3, 0);
  }

  hipMemsetAsync(vel, 0, (size_t)NQT*3*sizeof(float), stream);
  k_hatom<<<NAT, 128, 0, stream>>>(atom_feat, apW, apb, h_atom);
  k_temb<<<NQT/8, 256, 0, stream>>>(t_query, tW1, tb1, tW2, tb2, temb);
  k_hinit<<<NQT, 128, 0, stream>>>(x_t, atom_pos, qiW1, qib1, qiW2, qib2, hA);

  float* hc = hA; float* hn = hB;
  for (int i = 0; i < 4; i++){
    for (int half = 0; half < 2; half++){
      int j = 2*i + half;
      const int* es = half ? e_qq_s : e_aq_s;
      const int* et = half ? e_qq_t : e_aq_t;
      const int* pm = half ? perm_q : perm_a;
      int E = half ? EQQ : EAQ;
      const float* hsrc = half ? hc : h_atom;
      const float* psrc = half ? x_t : atom_pos;
      hipMemsetAsync(agg, 0, (size_t)NQT*128*sizeof(float), stream);
      k_edge<<<E/32, 256, 0, stream>>>(hsrc, hc, psrc, x_t, temb, es, et, pm,
          W1p + (size_t)j*98304, mW1 + (size_t)j*385*256, mb1 + (size_t)j*256,
          W2p + (size_t)j*32768, mb2 + (size_t)j*128,
          W3p + (size_t)j*8192,  cb1 + (size_t)j*64,
          cW2 + (size_t)j*64,    cb2 + (size_t)j,
          agg, vel);
      k_node<<<NQT/16, 256, 0, stream>>>(hc, agg,
          nW1 + (size_t)j*256*128, nb1 + (size_t)j*128,
          nW2 + (size_t)j*128*128, nb2 + (size_t)j*128,
          lng + (size_t)j*128,     lnb + (size_t)j*128, hn);
      float* tmp = hc; hc = hn; hn = tmp;
    }
  }
  k_out<<<NQT, 128, 0, stream>>>(hc, vel, voW1, vob1, voW2, vob2, out);
}

// Round 4
// 1625.776 us; speedup vs baseline: 1.3982x; 1.3982x over previous
//
#include <hip/hip_runtime.h>

#define NQT 16384
#define NAT 512
#define EAQ 131072
#define EQQ 262144

typedef short short8 __attribute__((ext_vector_type(8)));
typedef float float4v __attribute__((ext_vector_type(4)));

__device__ __forceinline__ float silu_f(float x){ return x / (1.f + __expf(-x)); }

__device__ __forceinline__ short f2bf(float f){
  union { float f; unsigned u; } v; v.f = f;
  unsigned r = v.u + 0x7fff + ((v.u >> 16) & 1);
  return (short)(r >> 16);
}
__device__ __forceinline__ float bf2f(short s){
  union { unsigned u; float f; } v;
  v.u = ((unsigned)(unsigned short)s) << 16;
  return v.f;
}

// ---------------- counting sort by tgt ----------------
__global__ __launch_bounds__(256) void k_hist(
    const int* __restrict__ etgt, int* __restrict__ hist, int E)
{
  int i = blockIdx.x*256 + threadIdx.x;
  if (i < E) atomicAdd(&hist[etgt[i]], 1);
}

__global__ __launch_bounds__(256) void k_scan(int* __restrict__ hist)
{
  __shared__ int part[256];
  int t = threadIdx.x;
  int base = t * 64;
  int s = 0;
  for (int i = 0; i < 64; i++) s += hist[base + i];
  part[t] = s;
  __syncthreads();
  for (int off = 1; off < 256; off <<= 1){
    int v = (t >= off) ? part[t - off] : 0;
    __syncthreads();
    part[t] += v;
    __syncthreads();
  }
  int run = (t == 0) ? 0 : part[t-1];
  for (int i = 0; i < 64; i++){
    int h = hist[base + i];
    hist[base + i] = run;
    run += h;
  }
}

__global__ __launch_bounds__(256) void k_place(
    const int* __restrict__ esrc, const int* __restrict__ etgt,
    int* __restrict__ cursor, int2* __restrict__ desc, int E)
{
  int i = blockIdx.x*256 + threadIdx.x;
  if (i < E){
    int tg = etgt[i];
    int pos = atomicAdd(&cursor[tg], 1);
    desc[pos] = make_int2(esrc[i], tg);
  }
}

// ---------------- weight packer -> MFMA B-frag bf16 ----------------
// layout: [ntiles][ksteps][64 lanes][8]; lane gives B[k=kk*32+(lane>>4)*8+j][n=nt*16+(lane&15)]
__global__ __launch_bounds__(256) void k_pack(
    const float* __restrict__ W, short* __restrict__ out,
    int rows, int cols, int ksteps, int ntiles, int total, int mode)
{
  int idx = blockIdx.x * 256 + threadIdx.x;
  if (idx >= total) return;
  int l8   = idx & 7;
  int lane = (idx >> 3) & 63;
  int kk   = (idx >> 9) % ksteps;
  int nt   = ((idx >> 9) / ksteps) % ntiles;
  int j    = idx / (512 * ksteps * ntiles);
  int k = kk*32 + (lane >> 4)*8 + l8;
  if (mode == 1) k += (k >= 256);                 // skip sq row
  else if (mode == 2) k = (k < 128) ? k + 128 : k + 129;  // [h_tgt | temb] rows of W1
  int n = nt*16 + (lane & 15);
  out[idx] = f2bf(W[(size_t)j*rows*cols + (size_t)k*cols + n]);
}

// ---------------- node pre-GEMM: out_bf16[M][256] = [Xa|Xb] @ Wpacked ----------------
template<int KSTEPS>
__global__ __launch_bounds__(256) void k_pre(
    const float* __restrict__ Xa, const float* __restrict__ Xb,
    const short* __restrict__ Wp, short* __restrict__ out)
{
  int t = threadIdx.x;
  int lane = t & 63, w = t >> 6;
  int mrow = lane & 15, quad = lane >> 4;
  int m0 = blockIdx.x*64 + w*16;

  short8 areg[KSTEPS];
  #pragma unroll
  for (int kk = 0; kk < KSTEPS; kk++){
    int k = kk*32 + quad*8;
    const float* bp;
    if (KSTEPS == 8 && kk >= 4) bp = Xb + (size_t)(m0+mrow)*128 + (k - 128);
    else                        bp = Xa + (size_t)(m0+mrow)*128 + k;
    float4 f0 = *(const float4*)(bp);
    float4 f1 = *(const float4*)(bp + 4);
    short8 s;
    s[0]=f2bf(f0.x); s[1]=f2bf(f0.y); s[2]=f2bf(f0.z); s[3]=f2bf(f0.w);
    s[4]=f2bf(f1.x); s[5]=f2bf(f1.y); s[6]=f2bf(f1.z); s[7]=f2bf(f1.w);
    areg[kk] = s;
  }
  #pragma unroll
  for (int nt = 0; nt < 16; nt++){
    float4v acc = {0.f,0.f,0.f,0.f};
    const short8* Bb = (const short8*)(Wp + ((size_t)nt*KSTEPS)*512 + lane*8);
    #pragma unroll
    for (int kk = 0; kk < KSTEPS; kk++)
      acc = __builtin_amdgcn_mfma_f32_16x16x32_bf16(areg[kk], Bb[kk*64], acc, 0, 0, 0);
    #pragma unroll
    for (int r = 0; r < 4; r++)
      out[(size_t)(m0 + quad*4 + r)*256 + nt*16 + mrow] = f2bf(acc[r]);
  }
}

// ---------------- h_atom ----------------
__global__ __launch_bounds__(128) void k_hatom(
    const float* __restrict__ feat, const float* __restrict__ W,
    const float* __restrict__ b, float* __restrict__ out)
{
  __shared__ float sf[256];
  int n = blockIdx.x, t = threadIdx.x;
  sf[t]       = feat[n*256 + t];
  sf[t + 128] = feat[n*256 + 128 + t];
  __syncthreads();
  float acc = b[t];
  for (int k = 0; k < 256; k++) acc += sf[k] * W[k*128 + t];
  out[n*128 + t] = acc;
}

// ---------------- t_emb ----------------
__global__ __launch_bounds__(256) void k_temb(
    const float* __restrict__ tq,
    const float* __restrict__ W1, const float* __restrict__ b1,
    const float* __restrict__ W2, const float* __restrict__ b2,
    float* __restrict__ temb)
{
  __shared__ float emb[128*8];
  __shared__ float hid[512*8];
  int t = threadIdx.x, n0 = blockIdx.x * 8;
  #pragma unroll
  for (int i = 0; i < 4; i++){
    int idx = t + 256*i;
    int k = idx >> 3, n = idx & 7;
    float tv = tq[n0 + n];
    int h = k & 63;
    float freq = __expf(-9.210340371976184f * (float)h * (1.f/63.f));
    float a = tv * freq;
    emb[idx] = (k < 64) ? __sinf(a) : __cosf(a);
  }
  __syncthreads();
  float acc[16];
  #pragma unroll
  for (int i = 0; i < 16; i++) acc[i] = 0.f;
  const float4* ev = (const float4*)emb;
  for (int k = 0; k < 128; k++){
    float wa = W1[k*512 + t];
    float wb = W1[k*512 + t + 256];
    float4 e0 = ev[k*2], e1 = ev[k*2 + 1];
    acc[0]+=wa*e0.x; acc[1]+=wa*e0.y; acc[2]+=wa*e0.z; acc[3]+=wa*e0.w;
    acc[4]+=wa*e1.x; acc[5]+=wa*e1.y; acc[6]+=wa*e1.z; acc[7]+=wa*e1.w;
    acc[8]+=wb*e0.x; acc[9]+=wb*e0.y; acc[10]+=wb*e0.z; acc[11]+=wb*e0.w;
    acc[12]+=wb*e1.x; acc[13]+=wb*e1.y; acc[14]+=wb*e1.z; acc[15]+=wb*e1.w;
  }
  float ba = b1[t], bb = b1[t + 256];
  #pragma unroll
  for (int n = 0; n < 8; n++){
    hid[t*8 + n]        = silu_f(acc[n] + ba);
    hid[(t+256)*8 + n]  = silu_f(acc[8+n] + bb);
  }
  __syncthreads();
  float a2[4] = {0.f,0.f,0.f,0.f};
  int c = t & 127, nh = t >> 7;
  const float4* hv = (const float4*)hid;
  for (int k = 0; k < 512; k++){
    float w = W2[k*128 + c];
    float4 h4 = hv[k*2 + nh];
    a2[0]+=w*h4.x; a2[1]+=w*h4.y; a2[2]+=w*h4.z; a2[3]+=w*h4.w;
  }
  float bc = b2[c];
  #pragma unroll
  for (int i = 0; i < 4; i++)
    temb[(size_t)(n0 + nh*4 + i)*128 + c] = a2[i] + bc;
}

// ---------------- h init ----------------
__global__ __launch_bounds__(128) void k_hinit(
    const float* __restrict__ x_t, const float* __restrict__ atom_pos,
    const float* __restrict__ W1, const float* __restrict__ b1,
    const float* __restrict__ W2, const float* __restrict__ b2,
    float* __restrict__ h)
{
  __shared__ float sh[128];
  __shared__ float sld;
  int n = blockIdx.x, t = threadIdx.x;
  float qx = x_t[n*3], qy = x_t[n*3+1], qz = x_t[n*3+2];
  float part = 0.f;
  if (t < 64){
    int a = (n >> 11)*64 + t;
    float dx = qx - atom_pos[a*3];
    float dy = qy - atom_pos[a*3+1];
    float dz = qz - atom_pos[a*3+2];
    part = dx*dx + dy*dy + dz*dz;
  }
  #pragma unroll
  for (int off = 32; off; off >>= 1) part += __shfl_down(part, off);
  if (t == 0) sld = log1pf(sqrtf(part * (1.f/64.f)) * 0.125f);
  __syncthreads();
  float ld = sld;
  sh[t] = silu_f(ld * W1[t] + b1[t]);
  __syncthreads();
  float acc = b2[t];
  for (int k = 0; k < 128; k++) acc += sh[k] * W2[k*128 + t];
  h[(size_t)n*128 + t] = acc;
}

// ---------------- EGNN edge kernel (pre-GEMM1 decomposed) ----------------
__global__ __launch_bounds__(256) void k_edge(
    const short* __restrict__ Psrc, const short* __restrict__ Ptgt,
    const float* __restrict__ pos_src, const float* __restrict__ pos_tgt,
    const int2* __restrict__ sdesc,
    const float* __restrict__ w1sq, const float* __restrict__ b1,
    const short* __restrict__ W2p, const float* __restrict__ b2,
    const short* __restrict__ W3p, const float* __restrict__ b3,
    const float* __restrict__ W4,  const float* __restrict__ b4,
    float* __restrict__ agg, float* __restrict__ vel)
{
  __shared__ __align__(16) short A2[32*264];   // hid bf16 [e][256] str 264; later msgf f32 str132 / h3 f32 str68
  __shared__ __align__(16) short A3[32*136];   // msg bf16 [e][128] str 136
  __shared__ float sb1[256], sw1[256];
  __shared__ float rel_s[32*3];
  __shared__ int   tgt_s[32];
  float* msgf = (float*)A2;
  float* h3   = (float*)A2;

  int t = threadIdx.x;
  int e0 = blockIdx.x * 32;

  sb1[t] = b1[t];
  sw1[t] = w1sq[t];
  __syncthreads();

  // ---- stage: pre1 = Psrc[src] + Ptgt[tgt] + sq*w1sq + b1 -> silu -> A2 bf16 ----
  {
    int e = t >> 3, l = t & 7;
    int2 d = sdesc[e0 + e];
    int src = d.x, tgt = d.y;
    float rx = pos_tgt[tgt*3+0] - pos_src[src*3+0];
    float ry = pos_tgt[tgt*3+1] - pos_src[src*3+1];
    float rz = pos_tgt[tgt*3+2] - pos_src[src*3+2];
    float sqv = rx*rx + ry*ry + rz*rz;
    if (l == 0){
      rel_s[e*3+0]=rx; rel_s[e*3+1]=ry; rel_s[e*3+2]=rz;
      tgt_s[e] = tgt;
    }
    const short8* ps = (const short8*)(Psrc + (size_t)src*256);
    const short8* pt = (const short8*)(Ptgt + (size_t)tgt*256);
    #pragma unroll
    for (int c = 0; c < 4; c++){
      int ci = c*8 + l;
      int n0 = ci*8;
      short8 a = ps[ci], b = pt[ci];
      short8 r;
      #pragma unroll
      for (int j = 0; j < 8; j++){
        int n = n0 + j;
        float v = bf2f(a[j]) + bf2f(b[j]) + sqv*sw1[n] + sb1[n];
        r[j] = f2bf(silu_f(v));
      }
      *(short8*)(A2 + e*264 + n0) = r;
    }
  }
  __syncthreads();

  int lane = t & 63, w = t >> 6;
  int mrow = lane & 15, quad = lane >> 4;

  // ---- GEMM2: (32x256)@(256x128), accs in regs ----
  float4v acc2[2][2];
  #pragma unroll
  for (int nti = 0; nti < 2; nti++){
    int nt = w*2 + nti;
    #pragma unroll
    for (int mt = 0; mt < 2; mt++){
      float4v acc = {0.f,0.f,0.f,0.f};
      const short8* Ab = (const short8*)(A2 + (mt*16 + mrow)*264 + quad*8);
      const short8* Bb = (const short8*)(W2p + (size_t)nt*8*512 + lane*8);
      #pragma unroll
      for (int kk = 0; kk < 8; kk++)
        acc = __builtin_amdgcn_mfma_f32_16x16x32_bf16(Ab[kk*4], Bb[kk*64], acc, 0, 0, 0);
      acc2[nti][mt] = acc;
    }
  }
  __syncthreads();   // A2 (hid) reads complete — region becomes msgf

  // ---- epilogue: silu -> msgf (f32) + A3 (bf16) ----
  #pragma unroll
  for (int nti = 0; nti < 2; nti++){
    int nt = w*2 + nti;
    int n = nt*16 + mrow;
    float b2n = b2[n];
    #pragma unroll
    for (int mt = 0; mt < 2; mt++){
      #pragma unroll
      for (int r = 0; r < 4; r++){
        int e = mt*16 + quad*4 + r;
        float v = silu_f(acc2[nti][mt][r] + b2n);
        msgf[e*132 + n] = v;
        A3[e*136 + n]   = f2bf(v);
      }
    }
  }
  __syncthreads();

  // ---- segmented agg reduction (edges sorted by tgt) ----
  {
    int c = t & 127, hh = t >> 7;
    int eb = hh*16;
    float run = 0.f;
    int cur = tgt_s[eb];
    for (int e = eb; e < eb + 16; e++){
      int tg = tgt_s[e];
      if (tg != cur){
        atomicAdd(&agg[(size_t)cur*128 + c], run);
        run = 0.f; cur = tg;
      }
      run += msgf[e*132 + c];
    }
    atomicAdd(&agg[(size_t)cur*128 + c], run);
  }
  __syncthreads();   // msgf reads complete — region becomes h3

  // ---- GEMM3: (32x128)@(128x64) + silu -> h3 (f32) ----
  {
    int nt = w;
    #pragma unroll
    for (int mt = 0; mt < 2; mt++){
      float4v acc = {0.f,0.f,0.f,0.f};
      const short8* Ab = (const short8*)(A3 + (mt*16 + mrow)*136 + quad*8);
      const short8* Bb = (const short8*)(W3p + (size_t)nt*4*512 + lane*8);
      #pragma unroll
      for (int kk = 0; kk < 4; kk++)
        acc = __builtin_amdgcn_mfma_f32_16x16x32_bf16(Ab[kk*4], Bb[kk*64], acc, 0, 0, 0);
      int n = nt*16 + mrow;
      float b3n = b3[n];
      #pragma unroll
      for (int r = 0; r < 4; r++){
        int e = mt*16 + quad*4 + r;
        h3[e*68 + n] = silu_f(acc[r] + b3n);
      }
    }
  }
  __syncthreads();

  // ---- GEMM4 (f32 dot-64) + tanh + vel scatter ----
  {
    int e = t >> 3, l = t & 7;
    float p = 0.f;
    #pragma unroll
    for (int i = 0; i < 8; i++){
      int k = l + 8*i;
      p += h3[e*68 + k] * W4[k];
    }
    p += __shfl_xor(p, 1);
    p += __shfl_xor(p, 2);
    p += __shfl_xor(p, 4);
    if (l == 0){
      float wv = tanhf(p + b4[0]);
      int tg = tgt_s[e];
      atomicAdd(&vel[tg*3+0], wv*rel_s[e*3+0]);
      atomicAdd(&vel[tg*3+1], wv*rel_s[e*3+1]);
      atomicAdd(&vel[tg*3+2], wv*rel_s[e*3+2]);
    }
  }
}

// ---------------- node update ----------------
__global__ __launch_bounds__(256) void k_node(
    const float* __restrict__ h, const float* __restrict__ agg,
    const float* __restrict__ W1, const float* __restrict__ b1,
    const float* __restrict__ W2, const float* __restrict__ b2,
    const float* __restrict__ g, const float* __restrict__ bb_,
    float* __restrict__ h_out)
{
  __shared__ float u[256*16];
  __shared__ float hid[128*16];
  __shared__ float r[16*128];
  int t = threadIdx.x;
  int n0 = blockIdx.x * 16;
  {
    int l = t & 15, n = t >> 4;
    const float* hr = h   + (size_t)(n0+n)*128;
    const float* ar = agg + (size_t)(n0+n)*128;
    #pragma unroll
    for (int i = 0; i < 8; i++){
      int k = l + 16*i;
      u[k*16 + n]         = hr[k];
      u[(128 + k)*16 + n] = ar[k];
    }
  }
  __syncthreads();
  int c = t & 63, q = t >> 6;
  {
    float acc[8];
    #pragma unroll
    for (int i = 0; i < 8; i++) acc[i] = 0.f;
    const float4* uv = (const float4*)u;
    for (int k = 0; k < 256; k++){
      float wa = W1[k*128 + c];
      float wb = W1[k*128 + c + 64];
      float4 u4 = uv[k*4 + q];
      acc[0]+=wa*u4.x; acc[1]+=wa*u4.y; acc[2]+=wa*u4.z; acc[3]+=wa*u4.w;
      acc[4]+=wb*u4.x; acc[5]+=wb*u4.y; acc[6]+=wb*u4.z; acc[7]+=wb*u4.w;
    }
    float ba = b1[c], bv = b1[c + 64];
    #pragma unroll
    for (int i = 0; i < 4; i++){
      int n = q*4 + i;
      hid[c*16 + n]        = silu_f(acc[i] + ba);
      hid[(c+64)*16 + n]   = silu_f(acc[4+i] + bv);
    }
  }
  __syncthreads();
  {
    float acc[8];
    #pragma unroll
    for (int i = 0; i < 8; i++) acc[i] = 0.f;
    const float4* hv = (const float4*)hid;
    for (int k = 0; k < 128; k++){
      float wa = W2[k*128 + c];
      float wb = W2[k*128 + c + 64];
      float4 h4 = hv[k*4 + q];
      acc[0]+=wa*h4.x; acc[1]+=wa*h4.y; acc[2]+=wa*h4.z; acc[3]+=wa*h4.w;
      acc[4]+=wb*h4.x; acc[5]+=wb*h4.y; acc[6]+=wb*h4.z; acc[7]+=wb*h4.w;
    }
    float ba = b2[c], bv = b2[c + 64];
    #pragma unroll
    for (int i = 0; i < 4; i++){
      int n = q*4 + i;
      r[n*128 + c]      = h[(size_t)(n0+n)*128 + c]      + acc[i]   + ba;
      r[n*128 + c + 64] = h[(size_t)(n0+n)*128 + c + 64] + acc[4+i] + bv;
    }
  }
  __syncthreads();
  {
    int lane = t & 63, wid = t >> 6;
    #pragma unroll
    for (int nn = 0; nn < 4; nn++){
      int n = wid*4 + nn;
      float a = r[n*128 + lane], b2v = r[n*128 + lane + 64];
      float s = a + b2v, ss = a*a + b2v*b2v;
      #pragma unroll
      for (int off = 1; off < 64; off <<= 1){
        s  += __shfl_xor(s, off);
        ss += __shfl_xor(ss, off);
      }
      float mean = s * (1.f/128.f);
      float var  = ss * (1.f/128.f) - mean*mean;
      float rstd = rsqrtf(var + 1e-5f);
      float* ho = h_out + (size_t)(n0+n)*128;
      ho[lane]      = (a   - mean)*rstd*g[lane]      + bb_[lane];
      ho[lane + 64] = (b2v - mean)*rstd*g[lane + 64] + bb_[lane + 64];
    }
  }
}

// ---------------- output ----------------
__global__ __launch_bounds__(128) void k_out(
    const float* __restrict__ h, const float* __restrict__ vel,
    const float* __restrict__ W1, const float* __restrict__ b1,
    const float* __restrict__ W2, const float* __restrict__ b2,
    float* __restrict__ out)
{
  __shared__ float sh[128];
  __shared__ float spart[2];
  int n = blockIdx.x, t = threadIdx.x;
  sh[t] = h[(size_t)n*128 + t];
  __syncthreads();
  float acc = b1[t];
  for (int k = 0; k < 128; k++) acc += sh[k] * W1[k*128 + t];
  float p = silu_f(acc) * W2[t];
  #pragma unroll
  for (int off = 32; off; off >>= 1) p += __shfl_down(p, off);
  if ((t & 63) == 0) spart[t >> 6] = p;
  __syncthreads();
  if (t < 3){
    float scale = spart[0] + spart[1] + b2[0];
    out[n*3 + t] = vel[n*3 + t] * scale;
  }
}

extern "C" void kernel_launch(void* const* d_in, const int* in_sizes, int n_in,
                              void* d_out, int out_size, void* d_ws, size_t ws_size,
                              hipStream_t stream)
{
  const float* x_t       = (const float*)d_in[0];
  const float* t_query   = (const float*)d_in[1];
  const float* atom_pos  = (const float*)d_in[2];
  const float* atom_feat = (const float*)d_in[3];
  const int*   e_aq_s = (const int*)d_in[4];
  const int*   e_aq_t = (const int*)d_in[5];
  const int*   e_qq_s = (const int*)d_in[6];
  const int*   e_qq_t = (const int*)d_in[7];
  const float* apW  = (const float*)d_in[8];
  const float* apb  = (const float*)d_in[9];
  const float* tW1  = (const float*)d_in[10];
  const float* tb1  = (const float*)d_in[11];
  const float* tW2  = (const float*)d_in[12];
  const float* tb2  = (const float*)d_in[13];
  const float* qiW1 = (const float*)d_in[14];
  const float* qib1 = (const float*)d_in[15];
  const float* qiW2 = (const float*)d_in[16];
  const float* qib2 = (const float*)d_in[17];
  const float* mW1  = (const float*)d_in[18];
  const float* mb1  = (const float*)d_in[19];
  const float* mW2  = (const float*)d_in[20];
  const float* mb2  = (const float*)d_in[21];
  const float* cW1  = (const float*)d_in[22];
  const float* cb1  = (const float*)d_in[23];
  const float* cW2  = (const float*)d_in[24];
  const float* cb2  = (const float*)d_in[25];
  const float* nW1  = (const float*)d_in[26];
  const float* nb1  = (const float*)d_in[27];
  const float* nW2  = (const float*)d_in[28];
  const float* nb2  = (const float*)d_in[29];
  const float* lng  = (const float*)d_in[30];
  const float* lnb  = (const float*)d_in[31];
  const float* voW1 = (const float*)d_in[32];
  const float* vob1 = (const float*)d_in[33];
  const float* voW2 = (const float*)d_in[34];
  const float* vob2 = (const float*)d_in[35];
  float* out = (float*)d_out;

  float* ws     = (float*)d_ws;
  float* h_atom = ws;                        // 65536
  float* temb   = h_atom + 65536;            // 2097152
  float* hA     = temb + 2097152;
  float* hB     = hA + 2097152;
  float* agg    = hB + 2097152;
  float* vel    = agg + 2097152;             // 49152
  short* W1ap   = (short*)(vel + 49152);     // 8*16*4*512  = 262144
  short* W1bcp  = W1ap + 262144;             // 8*16*8*512  = 524288
  short* W2p    = W1bcp + 524288;            // 262144
  short* W3p    = W2p + 262144;              // 65536
  short* Psrc   = W3p + 65536;               // 16384*256 = 4194304
  short* Ptgt   = Psrc + 4194304;            // 4194304
  int*   hist_a = (int*)(Ptgt + 4194304);    // 16384
  int*   hist_q = hist_a + 16384;            // 16384
  int2*  desc_a = (int2*)(hist_q + 16384);   // EAQ
  int2*  desc_q = desc_a + EAQ;              // EQQ

  // ---- edge sort by tgt -> sorted (src,tgt) descriptors ----
  hipMemsetAsync(hist_a, 0, 16384*sizeof(int), stream);
  hipMemsetAsync(hist_q, 0, 16384*sizeof(int), stream);
  k_hist<<<EAQ/256, 256, 0, stream>>>(e_aq_t, hist_a, EAQ);
  k_hist<<<EQQ/256, 256, 0, stream>>>(e_qq_t, hist_q, EQQ);
  k_scan<<<1, 256, 0, stream>>>(hist_a);
  k_scan<<<1, 256, 0, stream>>>(hist_q);
  k_place<<<EAQ/256, 256, 0, stream>>>(e_aq_s, e_aq_t, hist_a, desc_a, EAQ);
  k_place<<<EQQ/256, 256, 0, stream>>>(e_qq_s, e_qq_t, hist_q, desc_q, EQQ);

  // ---- weight packing ----
  k_pack<<<(262144+255)/256, 256, 0, stream>>>(mW1, W1ap,  385, 256, 4, 16, 262144, 0);
  k_pack<<<(524288+255)/256, 256, 0, stream>>>(mW1, W1bcp, 385, 256, 8, 16, 524288, 2);
  k_pack<<<(262144+255)/256, 256, 0, stream>>>(mW2, W2p,   256, 128, 8,  8, 262144, 0);
  k_pack<<<( 65536+255)/256, 256, 0, stream>>>(cW1, W3p,   128,  64, 4,  4,  65536, 0);

  hipMemsetAsync(vel, 0, (size_t)NQT*3*sizeof(float), stream);
  k_hatom<<<NAT, 128, 0, stream>>>(atom_feat, apW, apb, h_atom);
  k_temb<<<NQT/8, 256, 0, stream>>>(t_query, tW1, tb1, tW2, tb2, temb);
  k_hinit<<<NQT, 128, 0, stream>>>(x_t, atom_pos, qiW1, qib1, qiW2, qib2, hA);

  float* hc = hA; float* hn = hB;
  for (int i = 0; i < 4; i++){
    for (int half = 0; half < 2; half++){
      int j = 2*i + half;
      const int2* dsc = half ? desc_q : desc_a;
      int E = half ? EQQ : EAQ;
      const float* hsrc = half ? hc : h_atom;
      const float* psrc = half ? x_t : atom_pos;
      int Msrc = half ? NQT : NAT;

      // node pre-GEMMs for edge GEMM1 decomposition
      k_pre<4><<<Msrc/64, 256, 0, stream>>>(hsrc, nullptr, W1ap + (size_t)j*32768, Psrc);
      k_pre<8><<<NQT/64, 256, 0, stream>>>(hc, temb, W1bcp + (size_t)j*65536, Ptgt);

      hipMemsetAsync(agg, 0, (size_t)NQT*128*sizeof(float), stream);
      k_edge<<<E/32, 256, 0, stream>>>(Psrc, Ptgt, psrc, x_t, dsc,
          mW1 + (size_t)j*385*256 + 65536, mb1 + (size_t)j*256,
          W2p + (size_t)j*32768, mb2 + (size_t)j*128,
          W3p + (size_t)j*8192,  cb1 + (size_t)j*64,
          cW2 + (size_t)j*64,    cb2 + (size_t)j,
          agg, vel);
      k_node<<<NQT/16, 256, 0, stream>>>(hc, agg,
          nW1 + (size_t)j*256*128, nb1 + (size_t)j*128,
          nW2 + (size_t)j*128*128, nb2 + (size_t)j*128,
          lng + (size_t)j*128,     lnb + (size_t)j*128, hn);
      float* tmp = hc; hc = hn; hn = tmp;
    }
  }
  k_out<<<NQT, 128, 0, stream>>>(hc, vel, voW1, vob1, voW2, vob2, out);
}

// Round 5
// 1433.019 us; speedup vs baseline: 1.5862x; 1.1345x over previous
//
#include <hip/hip_runtime.h>

#define NQT 16384
#define NAT 512
#define EAQ 131072
#define EQQ 262144

typedef short short8 __attribute__((ext_vector_type(8)));
typedef float float4v __attribute__((ext_vector_type(4)));

__device__ __forceinline__ float silu_f(float x){ return x / (1.f + __expf(-x)); }

__device__ __forceinline__ short f2bf(float f){
  union { float f; unsigned u; } v; v.f = f;
  unsigned r = v.u + 0x7fff + ((v.u >> 16) & 1);
  return (short)(r >> 16);
}
__device__ __forceinline__ float bf2f(short s){
  union { unsigned u; float f; } v;
  v.u = ((unsigned)(unsigned short)s) << 16;
  return v.f;
}

// ---------------- counting sort by tgt ----------------
__global__ __launch_bounds__(256) void k_hist(
    const int* __restrict__ etgt, int* __restrict__ hist, int E)
{
  int i = blockIdx.x*256 + threadIdx.x;
  if (i < E) atomicAdd(&hist[etgt[i]], 1);
}

__global__ __launch_bounds__(256) void k_scan(int* __restrict__ hist)
{
  __shared__ int part[256];
  int t = threadIdx.x;
  int base = t * 64;
  int s = 0;
  for (int i = 0; i < 64; i++) s += hist[base + i];
  part[t] = s;
  __syncthreads();
  for (int off = 1; off < 256; off <<= 1){
    int v = (t >= off) ? part[t - off] : 0;
    __syncthreads();
    part[t] += v;
    __syncthreads();
  }
  int run = (t == 0) ? 0 : part[t-1];
  for (int i = 0; i < 64; i++){
    int h = hist[base + i];
    hist[base + i] = run;
    run += h;
  }
}

__global__ __launch_bounds__(256) void k_place(
    const int* __restrict__ esrc, const int* __restrict__ etgt,
    int* __restrict__ cursor, int2* __restrict__ desc, int E)
{
  int i = blockIdx.x*256 + threadIdx.x;
  if (i < E){
    int tg = etgt[i];
    int pos = atomicAdd(&cursor[tg], 1);
    desc[pos] = make_int2(esrc[i], tg);
  }
}

// ---------------- weight packer -> MFMA B-frag bf16 ----------------
// layout: [ntiles][ksteps][64 lanes][8]; lane gives B[k=kk*32+(lane>>4)*8+j][n=nt*16+(lane&15)]
__global__ __launch_bounds__(256) void k_pack(
    const float* __restrict__ W, short* __restrict__ out,
    int rows, int cols, int ksteps, int ntiles, int total, int mode)
{
  int idx = blockIdx.x * 256 + threadIdx.x;
  if (idx >= total) return;
  int l8   = idx & 7;
  int lane = (idx >> 3) & 63;
  int kk   = (idx >> 9) % ksteps;
  int nt   = ((idx >> 9) / ksteps) % ntiles;
  int j    = idx / (512 * ksteps * ntiles);
  int k = kk*32 + (lane >> 4)*8 + l8;
  if (mode == 1) k += (k >= 256);                 // skip sq row
  else if (mode == 2) k = (k < 128) ? k + 128 : k + 129;  // [h_tgt | temb] rows of W1
  int n = nt*16 + (lane & 15);
  out[idx] = f2bf(W[(size_t)j*rows*cols + (size_t)k*cols + n]);
}

// ---------------- node pre-GEMM: out_bf16[M][256] = [Xa|Xb] @ Wpacked (+bias) ----------------
template<int KSTEPS>
__global__ __launch_bounds__(256) void k_pre(
    const float* __restrict__ Xa, const float* __restrict__ Xb,
    const float* __restrict__ bias,
    const short* __restrict__ Wp, short* __restrict__ out)
{
  int t = threadIdx.x;
  int lane = t & 63, w = t >> 6;
  int mrow = lane & 15, quad = lane >> 4;
  int m0 = blockIdx.x*64 + w*16;

  short8 areg[KSTEPS];
  #pragma unroll
  for (int kk = 0; kk < KSTEPS; kk++){
    int k = kk*32 + quad*8;
    const float* bp;
    if (KSTEPS == 8 && kk >= 4) bp = Xb + (size_t)(m0+mrow)*128 + (k - 128);
    else                        bp = Xa + (size_t)(m0+mrow)*128 + k;
    float4 f0 = *(const float4*)(bp);
    float4 f1 = *(const float4*)(bp + 4);
    short8 s;
    s[0]=f2bf(f0.x); s[1]=f2bf(f0.y); s[2]=f2bf(f0.z); s[3]=f2bf(f0.w);
    s[4]=f2bf(f1.x); s[5]=f2bf(f1.y); s[6]=f2bf(f1.z); s[7]=f2bf(f1.w);
    areg[kk] = s;
  }
  #pragma unroll
  for (int nt = 0; nt < 16; nt++){
    float4v acc = {0.f,0.f,0.f,0.f};
    const short8* Bb = (const short8*)(Wp + ((size_t)nt*KSTEPS)*512 + lane*8);
    #pragma unroll
    for (int kk = 0; kk < KSTEPS; kk++)
      acc = __builtin_amdgcn_mfma_f32_16x16x32_bf16(areg[kk], Bb[kk*64], acc, 0, 0, 0);
    float bv = bias ? bias[nt*16 + mrow] : 0.f;
    #pragma unroll
    for (int r = 0; r < 4; r++)
      out[(size_t)(m0 + quad*4 + r)*256 + nt*16 + mrow] = f2bf(acc[r] + bv);
  }
}

// ---------------- h_atom ----------------
__global__ __launch_bounds__(128) void k_hatom(
    const float* __restrict__ feat, const float* __restrict__ W,
    const float* __restrict__ b, float* __restrict__ out)
{
  __shared__ float sf[256];
  int n = blockIdx.x, t = threadIdx.x;
  sf[t]       = feat[n*256 + t];
  sf[t + 128] = feat[n*256 + 128 + t];
  __syncthreads();
  float acc = b[t];
  for (int k = 0; k < 256; k++) acc += sf[k] * W[k*128 + t];
  out[n*128 + t] = acc;
}

// ---------------- t_emb (MFMA) : 32 nodes/block ----------------
__global__ __launch_bounds__(256) void k_temb(
    const float* __restrict__ tq,
    const short* __restrict__ W1p, const float* __restrict__ b1,
    const short* __restrict__ W2p, const float* __restrict__ b2,
    float* __restrict__ temb)
{
  __shared__ __align__(16) short A[32*136];   // emb bf16 [n][128] stride 136
  __shared__ __align__(16) short B[32*528];   // hid bf16 [n][512] stride 528
  int t = threadIdx.x;
  int n0 = blockIdx.x * 32;

  { // stage emb
    int row = t >> 3, l = t & 7;
    float tv = tq[n0 + row];
    short* o = A + row*136;
    #pragma unroll
    for (int i = 0; i < 16; i++){
      int k = l*16 + i;
      int h = k & 63;
      float freq = __expf(-9.210340371976184f * (float)h * (1.f/63.f));
      float a = tv * freq;
      float v = (k < 64) ? __sinf(a) : __cosf(a);
      o[k] = f2bf(v);
    }
  }
  __syncthreads();

  int lane = t & 63, w = t >> 6;
  int mrow = lane & 15, quad = lane >> 4;

  // GEMM1: (32x128)@(128x512) + silu -> B
  for (int nti = 0; nti < 8; nti++){
    int nt = w*8 + nti;
    #pragma unroll
    for (int mt = 0; mt < 2; mt++){
      float4v acc = {0.f,0.f,0.f,0.f};
      const short8* Ab = (const short8*)(A + (mt*16 + mrow)*136 + quad*8);
      const short8* Bb = (const short8*)(W1p + (size_t)nt*4*512 + lane*8);
      #pragma unroll
      for (int kk = 0; kk < 4; kk++)
        acc = __builtin_amdgcn_mfma_f32_16x16x32_bf16(Ab[kk*4], Bb[kk*64], acc, 0, 0, 0);
      int n = nt*16 + mrow;
      float b1n = b1[n];
      #pragma unroll
      for (int r = 0; r < 4; r++)
        B[(mt*16 + quad*4 + r)*528 + n] = f2bf(silu_f(acc[r] + b1n));
    }
  }
  __syncthreads();

  // GEMM2: (32x512)@(512x128) -> temb
  #pragma unroll
  for (int nti = 0; nti < 2; nti++){
    int nt = w*2 + nti;
    #pragma unroll
    for (int mt = 0; mt < 2; mt++){
      float4v acc = {0.f,0.f,0.f,0.f};
      const short8* Ab = (const short8*)(B + (mt*16 + mrow)*528 + quad*8);
      const short8* Bb = (const short8*)(W2p + (size_t)nt*16*512 + lane*8);
      #pragma unroll
      for (int kk = 0; kk < 16; kk++)
        acc = __builtin_amdgcn_mfma_f32_16x16x32_bf16(Ab[kk*4], Bb[kk*64], acc, 0, 0, 0);
      int n = nt*16 + mrow;
      float b2n = b2[n];
      #pragma unroll
      for (int r = 0; r < 4; r++)
        temb[(size_t)(n0 + mt*16 + quad*4 + r)*128 + n] = acc[r] + b2n;
    }
  }
}

// ---------------- h init ----------------
__global__ __launch_bounds__(128) void k_hinit(
    const float* __restrict__ x_t, const float* __restrict__ atom_pos,
    const float* __restrict__ W1, const float* __restrict__ b1,
    const float* __restrict__ W2, const float* __restrict__ b2,
    float* __restrict__ h)
{
  __shared__ float sh[128];
  __shared__ float sld;
  int n = blockIdx.x, t = threadIdx.x;
  float qx = x_t[n*3], qy = x_t[n*3+1], qz = x_t[n*3+2];
  float part = 0.f;
  if (t < 64){
    int a = (n >> 11)*64 + t;
    float dx = qx - atom_pos[a*3];
    float dy = qy - atom_pos[a*3+1];
    float dz = qz - atom_pos[a*3+2];
    part = dx*dx + dy*dy + dz*dz;
  }
  #pragma unroll
  for (int off = 32; off; off >>= 1) part += __shfl_down(part, off);
  if (t == 0) sld = log1pf(sqrtf(part * (1.f/64.f)) * 0.125f);
  __syncthreads();
  float ld = sld;
  sh[t] = silu_f(ld * W1[t] + b1[t]);
  __syncthreads();
  float acc = b2[t];
  for (int k = 0; k < 128; k++) acc += sh[k] * W2[k*128 + t];
  h[(size_t)n*128 + t] = acc;
}

// ---------------- EGNN edge kernel ----------------
__global__ __launch_bounds__(256) void k_edge(
    const short* __restrict__ Psrc, const short* __restrict__ Ptgt,
    const float* __restrict__ pos_src, const float* __restrict__ pos_tgt,
    const int2* __restrict__ sdesc,
    const float* __restrict__ w1sq,
    const short* __restrict__ W2p, const float* __restrict__ b2,
    const short* __restrict__ W3p, const float* __restrict__ b3,
    const float* __restrict__ W4,  const float* __restrict__ b4,
    float* __restrict__ agg, float* __restrict__ vel)
{
  __shared__ __align__(16) short A2[32*264];   // hid bf16 [e][256] str 264; later h3 f32 [e][64] str 68
  __shared__ __align__(16) short A3[32*136];   // msg bf16 [e][128] str 136
  __shared__ float sw1[256];
  __shared__ float rel_s[32*3];
  __shared__ int   tgt_s[32];
  float* h3 = (float*)A2;

  int t = threadIdx.x;
  int e0 = blockIdx.x * 32;

  sw1[t] = w1sq[t];
  __syncthreads();

  // ---- stage: pre1 = Psrc[src] + Ptgt[tgt](+b1 folded) + sq*w1sq -> silu -> A2 ----
  {
    int e = t >> 3, l = t & 7;
    int2 d = sdesc[e0 + e];
    int src = d.x, tgt = d.y;
    float rx = pos_tgt[tgt*3+0] - pos_src[src*3+0];
    float ry = pos_tgt[tgt*3+1] - pos_src[src*3+1];
    float rz = pos_tgt[tgt*3+2] - pos_src[src*3+2];
    float sqv = rx*rx + ry*ry + rz*rz;
    if (l == 0){
      rel_s[e*3+0]=rx; rel_s[e*3+1]=ry; rel_s[e*3+2]=rz;
      tgt_s[e] = tgt;
    }
    const short8* ps = (const short8*)(Psrc + (size_t)src*256);
    const short8* pt = (const short8*)(Ptgt + (size_t)tgt*256);
    #pragma unroll
    for (int c = 0; c < 4; c++){
      int ci = c*8 + l;
      int n0 = ci*8;
      short8 a = ps[ci], b = pt[ci];
      short8 r;
      #pragma unroll
      for (int j = 0; j < 8; j++){
        int n = n0 + j;
        float v = bf2f(a[j]) + bf2f(b[j]) + sqv*sw1[n];
        r[j] = f2bf(silu_f(v));
      }
      *(short8*)(A2 + e*264 + n0) = r;
    }
  }
  __syncthreads();

  int lane = t & 63, w = t >> 6;
  int mrow = lane & 15, quad = lane >> 4;

  // ---- GEMM2: (32x256)@(256x128), accs in regs ----
  float4v acc2[2][2];
  #pragma unroll
  for (int nti = 0; nti < 2; nti++){
    int nt = w*2 + nti;
    #pragma unroll
    for (int mt = 0; mt < 2; mt++){
      float4v acc = {0.f,0.f,0.f,0.f};
      const short8* Ab = (const short8*)(A2 + (mt*16 + mrow)*264 + quad*8);
      const short8* Bb = (const short8*)(W2p + (size_t)nt*8*512 + lane*8);
      #pragma unroll
      for (int kk = 0; kk < 8; kk++)
        acc = __builtin_amdgcn_mfma_f32_16x16x32_bf16(Ab[kk*4], Bb[kk*64], acc, 0, 0, 0);
      acc2[nti][mt] = acc;
    }
  }

  // ---- epilogue: silu -> A3 (bf16) ----
  #pragma unroll
  for (int nti = 0; nti < 2; nti++){
    int nt = w*2 + nti;
    int n = nt*16 + mrow;
    float b2n = b2[n];
    #pragma unroll
    for (int mt = 0; mt < 2; mt++){
      #pragma unroll
      for (int r = 0; r < 4; r++){
        int e = mt*16 + quad*4 + r;
        A3[e*136 + n] = f2bf(silu_f(acc2[nti][mt][r] + b2n));
      }
    }
  }
  __syncthreads();

  // ---- segmented agg reduction (edges sorted by tgt), from bf16 msg ----
  {
    int c = t & 127, hh = t >> 7;
    int eb = hh*16;
    float run = 0.f;
    int cur = tgt_s[eb];
    for (int e = eb; e < eb + 16; e++){
      int tg = tgt_s[e];
      if (tg != cur){
        atomicAdd(&agg[(size_t)cur*128 + c], run);
        run = 0.f; cur = tg;
      }
      run += bf2f(A3[e*136 + c]);
    }
    atomicAdd(&agg[(size_t)cur*128 + c], run);
  }
  __syncthreads();   // A2 reads long done — region becomes h3

  // ---- GEMM3: (32x128)@(128x64) + silu -> h3 (f32) ----
  {
    int nt = w;
    #pragma unroll
    for (int mt = 0; mt < 2; mt++){
      float4v acc = {0.f,0.f,0.f,0.f};
      const short8* Ab = (const short8*)(A3 + (mt*16 + mrow)*136 + quad*8);
      const short8* Bb = (const short8*)(W3p + (size_t)nt*4*512 + lane*8);
      #pragma unroll
      for (int kk = 0; kk < 4; kk++)
        acc = __builtin_amdgcn_mfma_f32_16x16x32_bf16(Ab[kk*4], Bb[kk*64], acc, 0, 0, 0);
      int n = nt*16 + mrow;
      float b3n = b3[n];
      #pragma unroll
      for (int r = 0; r < 4; r++){
        int e = mt*16 + quad*4 + r;
        h3[e*68 + n] = silu_f(acc[r] + b3n);
      }
    }
  }
  __syncthreads();

  // ---- GEMM4 (f32 dot-64) + tanh + vel scatter ----
  {
    int e = t >> 3, l = t & 7;
    float p = 0.f;
    #pragma unroll
    for (int i = 0; i < 8; i++){
      int k = l + 8*i;
      p += h3[e*68 + k] * W4[k];
    }
    p += __shfl_xor(p, 1);
    p += __shfl_xor(p, 2);
    p += __shfl_xor(p, 4);
    if (l == 0){
      float wv = tanhf(p + b4[0]);
      int tg = tgt_s[e];
      atomicAdd(&vel[tg*3+0], wv*rel_s[e*3+0]);
      atomicAdd(&vel[tg*3+1], wv*rel_s[e*3+1]);
      atomicAdd(&vel[tg*3+2], wv*rel_s[e*3+2]);
    }
  }
}

// ---------------- node update (MFMA): 32 nodes/block ----------------
__global__ __launch_bounds__(256) void k_node(
    const float* __restrict__ h, const float* __restrict__ agg,
    const short* __restrict__ W1p, const float* __restrict__ b1,
    const short* __restrict__ W2p, const float* __restrict__ b2,
    const float* __restrict__ g, const float* __restrict__ bb_,
    float* __restrict__ h_out)
{
  __shared__ __align__(16) short A[32*264];   // u bf16 [n][256] str 264; later r f32 [n][128] str 132
  __shared__ __align__(16) short B[32*136];   // hid bf16 [n][128] str 136
  float* r = (float*)A;
  int t = threadIdx.x;
  int n0 = blockIdx.x * 32;

  { // stage u = [h|agg] bf16
    int row = t >> 3, l = t & 7;
    const float4* hr = (const float4*)(h   + (size_t)(n0+row)*128);
    const float4* ar = (const float4*)(agg + (size_t)(n0+row)*128);
    short* o = A + row*264;
    #pragma unroll
    for (int i = 0; i < 4; i++){
      int k4 = l + 8*i;
      float4 a = hr[k4], b = ar[k4];
      short8 s;
      s[0]=f2bf(a.x); s[1]=f2bf(a.y); s[2]=f2bf(a.z); s[3]=f2bf(a.w);
      s[4]=f2bf(b.x); s[5]=f2bf(b.y); s[6]=f2bf(b.z); s[7]=f2bf(b.w);
      *(short8*)(o + k4*4)       = (short8){s[0],s[1],s[2],s[3],0,0,0,0}; // placeholder
    }
  }
  // redo staging cleanly (the above partial writes would be wrong) — overwrite:
  {
    int row = t >> 3, l = t & 7;
    const float4* hr = (const float4*)(h   + (size_t)(n0+row)*128);
    const float4* ar = (const float4*)(agg + (size_t)(n0+row)*128);
    short* o = A + row*264;
    #pragma unroll
    for (int i = 0; i < 4; i++){
      int k4 = l + 8*i;
      float4 a = hr[k4];
      short4 s4;
      short sa0=f2bf(a.x), sa1=f2bf(a.y), sa2=f2bf(a.z), sa3=f2bf(a.w);
      o[k4*4+0]=sa0; o[k4*4+1]=sa1; o[k4*4+2]=sa2; o[k4*4+3]=sa3;
      float4 b = ar[k4];
      o[128 + k4*4+0]=f2bf(b.x); o[128 + k4*4+1]=f2bf(b.y);
      o[128 + k4*4+2]=f2bf(b.z); o[128 + k4*4+3]=f2bf(b.w);
    }
  }
  __syncthreads();

  int lane = t & 63, w = t >> 6;
  int mrow = lane & 15, quad = lane >> 4;

  // GEMM_A: (32x256)@(256x128), accs in regs
  float4v accA[2][2];
  #pragma unroll
  for (int nti = 0; nti < 2; nti++){
    int nt = w*2 + nti;
    #pragma unroll
    for (int mt = 0; mt < 2; mt++){
      float4v acc = {0.f,0.f,0.f,0.f};
      const short8* Ab = (const short8*)(A + (mt*16 + mrow)*264 + quad*8);
      const short8* Bb = (const short8*)(W1p + (size_t)nt*8*512 + lane*8);
      #pragma unroll
      for (int kk = 0; kk < 8; kk++)
        acc = __builtin_amdgcn_mfma_f32_16x16x32_bf16(Ab[kk*4], Bb[kk*64], acc, 0, 0, 0);
      accA[nti][mt] = acc;
    }
  }
  __syncthreads();   // A reads done

  // epilogue: silu -> B
  #pragma unroll
  for (int nti = 0; nti < 2; nti++){
    int n = (w*2 + nti)*16 + mrow;
    float b1n = b1[n];
    #pragma unroll
    for (int mt = 0; mt < 2; mt++){
      #pragma unroll
      for (int rr = 0; rr < 4; rr++){
        int e = mt*16 + quad*4 + rr;
        B[e*136 + n] = f2bf(silu_f(accA[nti][mt][rr] + b1n));
      }
    }
  }
  __syncthreads();

  // GEMM_B: (32x128)@(128x128) -> residual -> r (aliases A)
  #pragma unroll
  for (int nti = 0; nti < 2; nti++){
    int nt = w*2 + nti;
    #pragma unroll
    for (int mt = 0; mt < 2; mt++){
      float4v acc = {0.f,0.f,0.f,0.f};
      const short8* Ab = (const short8*)(B + (mt*16 + mrow)*136 + quad*8);
      const short8* Bb = (const short8*)(W2p + (size_t)nt*4*512 + lane*8);
      #pragma unroll
      for (int kk = 0; kk < 4; kk++)
        acc = __builtin_amdgcn_mfma_f32_16x16x32_bf16(Ab[kk*4], Bb[kk*64], acc, 0, 0, 0);
      int n = nt*16 + mrow;
      float b2n = b2[n];
      #pragma unroll
      for (int rr = 0; rr < 4; rr++){
        int e = mt*16 + quad*4 + rr;
        r[e*132 + n] = h[(size_t)(n0+e)*128 + n] + acc[rr] + b2n;
      }
    }
  }
  __syncthreads();

  // LayerNorm: one wave handles 8 rows, 2 cols/lane
  {
    int lane2 = t & 63, wid = t >> 6;
    #pragma unroll
    for (int nn = 0; nn < 8; nn++){
      int row = wid*8 + nn;
      float a = r[row*132 + lane2], bv = r[row*132 + lane2 + 64];
      float s = a + bv, ss = a*a + bv*bv;
      #pragma unroll
      for (int off = 1; off < 64; off <<= 1){
        s  += __shfl_xor(s, off);
        ss += __shfl_xor(ss, off);
      }
      float mean = s * (1.f/128.f);
      float var  = ss * (1.f/128.f) - mean*mean;
      float rstd = rsqrtf(var + 1e-5f);
      float* ho = h_out + (size_t)(n0+row)*128;
      ho[lane2]      = (a  - mean)*rstd*g[lane2]      + bb_[lane2];
      ho[lane2 + 64] = (bv - mean)*rstd*g[lane2 + 64] + bb_[lane2 + 64];
    }
  }
}

// ---------------- output ----------------
__global__ __launch_bounds__(128) void k_out(
    const float* __restrict__ h, const float* __restrict__ vel,
    const float* __restrict__ W1, const float* __restrict__ b1,
    const float* __restrict__ W2, const float* __restrict__ b2,
    float* __restrict__ out)
{
  __shared__ float sh[128];
  __shared__ float spart[2];
  int n = blockIdx.x, t = threadIdx.x;
  sh[t] = h[(size_t)n*128 + t];
  __syncthreads();
  float acc = b1[t];
  for (int k = 0; k < 128; k++) acc += sh[k] * W1[k*128 + t];
  float p = silu_f(acc) * W2[t];
  #pragma unroll
  for (int off = 32; off; off >>= 1) p += __shfl_down(p, off);
  if ((t & 63) == 0) spart[t >> 6] = p;
  __syncthreads();
  if (t < 3){
    float scale = spart[0] + spart[1] + b2[0];
    out[n*3 + t] = vel[n*3 + t] * scale;
  }
}

extern "C" void kernel_launch(void* const* d_in, const int* in_sizes, int n_in,
                              void* d_out, int out_size, void* d_ws, size_t ws_size,
                              hipStream_t stream)
{
  const float* x_t       = (const float*)d_in[0];
  const float* t_query   = (const float*)d_in[1];
  const float* atom_pos  = (const float*)d_in[2];
  const float* atom_feat = (const float*)d_in[3];
  const int*   e_aq_s = (const int*)d_in[4];
  const int*   e_aq_t = (const int*)d_in[5];
  const int*   e_qq_s = (const int*)d_in[6];
  const int*   e_qq_t = (const int*)d_in[7];
  const float* apW  = (const float*)d_in[8];
  const float* apb  = (const float*)d_in[9];
  const float* tW1  = (const float*)d_in[10];
  const float* tb1  = (const float*)d_in[11];
  const float* tW2  = (const float*)d_in[12];
  const float* tb2  = (const float*)d_in[13];
  const float* qiW1 = (const float*)d_in[14];
  const float* qib1 = (const float*)d_in[15];
  const float* qiW2 = (const float*)d_in[16];
  const float* qib2 = (const float*)d_in[17];
  const float* mW1  = (const float*)d_in[18];
  const float* mb1  = (const float*)d_in[19];
  const float* mW2  = (const float*)d_in[20];
  const float* mb2  = (const float*)d_in[21];
  const float* cW1  = (const float*)d_in[22];
  const float* cb1  = (const float*)d_in[23];
  const float* cW2  = (const float*)d_in[24];
  const float* cb2  = (const float*)d_in[25];
  const float* nW1  = (const float*)d_in[26];
  const float* nb1  = (const float*)d_in[27];
  const float* nW2  = (const float*)d_in[28];
  const float* nb2  = (const float*)d_in[29];
  const float* lng  = (const float*)d_in[30];
  const float* lnb  = (const float*)d_in[31];
  const float* voW1 = (const float*)d_in[32];
  const float* vob1 = (const float*)d_in[33];
  const float* voW2 = (const float*)d_in[34];
  const float* vob2 = (const float*)d_in[35];
  float* out = (float*)d_out;

  float* ws     = (float*)d_ws;
  float* h_atom = ws;                        // 65536
  float* temb   = h_atom + 65536;            // 2097152
  float* hA     = temb + 2097152;
  float* hB     = hA + 2097152;
  float* agg    = hB + 2097152;
  float* vel    = agg + 2097152;             // 49152
  short* W1ap   = (short*)(vel + 49152);     // 262144
  short* W1bcp  = W1ap + 262144;             // 524288
  short* W2p    = W1bcp + 524288;            // 262144
  short* W3p    = W2p + 262144;              // 65536
  short* nW1p   = W3p + 65536;               // 262144
  short* nW2p   = nW1p + 262144;             // 131072
  short* tW1p   = nW2p + 131072;             // 65536
  short* tW2p   = tW1p + 65536;              // 65536
  short* Psrc   = tW2p + 65536;              // 4194304
  short* Ptgt   = Psrc + 4194304;            // 4194304
  int*   hist_a = (int*)(Ptgt + 4194304);    // 16384
  int*   hist_q = hist_a + 16384;            // 16384
  int2*  desc_a = (int2*)(hist_q + 16384);   // EAQ
  int2*  desc_q = desc_a + EAQ;              // EQQ

  // ---- edge sort by tgt -> sorted (src,tgt) descriptors ----
  hipMemsetAsync(hist_a, 0, 16384*sizeof(int), stream);
  hipMemsetAsync(hist_q, 0, 16384*sizeof(int), stream);
  k_hist<<<EAQ/256, 256, 0, stream>>>(e_aq_t, hist_a, EAQ);
  k_hist<<<EQQ/256, 256, 0, stream>>>(e_qq_t, hist_q, EQQ);
  k_scan<<<1, 256, 0, stream>>>(hist_a);
  k_scan<<<1, 256, 0, stream>>>(hist_q);
  k_place<<<EAQ/256, 256, 0, stream>>>(e_aq_s, e_aq_t, hist_a, desc_a, EAQ);
  k_place<<<EQQ/256, 256, 0, stream>>>(e_qq_s, e_qq_t, hist_q, desc_q, EQQ);

  // ---- weight packing ----
  k_pack<<<(262144+255)/256, 256, 0, stream>>>(mW1, W1ap,  385, 256, 4, 16, 262144, 0);
  k_pack<<<(524288+255)/256, 256, 0, stream>>>(mW1, W1bcp, 385, 256, 8, 16, 524288, 2);
  k_pack<<<(262144+255)/256, 256, 0, stream>>>(mW2, W2p,   256, 128, 8,  8, 262144, 0);
  k_pack<<<( 65536+255)/256, 256, 0, stream>>>(cW1, W3p,   128,  64, 4,  4,  65536, 0);
  k_pack<<<(262144+255)/256, 256, 0, stream>>>(nW1, nW1p,  256, 128, 8,  8, 262144, 0);
  k_pack<<<(131072+255)/256, 256, 0, stream>>>(nW2, nW2p,  128, 128, 4,  8, 131072, 0);
  k_pack<<<( 65536+255)/256, 256, 0, stream>>>(tW1, tW1p,  128, 512, 4, 32,  65536, 0);
  k_pack<<<( 65536+255)/256, 256, 0, stream>>>(tW2, tW2p,  512, 128, 16, 8,  65536, 0);

  hipMemsetAsync(vel, 0, (size_t)NQT*3*sizeof(float), stream);
  k_hatom<<<NAT, 128, 0, stream>>>(atom_feat, apW, apb, h_atom);
  k_temb<<<NQT/32, 256, 0, stream>>>(t_query, tW1p, tb1, tW2p, tb2, temb);
  k_hinit<<<NQT, 128, 0, stream>>>(x_t, atom_pos, qiW1, qib1, qiW2, qib2, hA);

  float* hc = hA; float* hn = hB;
  for (int i = 0; i < 4; i++){
    for (int half = 0; half < 2; half++){
      int j = 2*i + half;
      const int2* dsc = half ? desc_q : desc_a;
      int E = half ? EQQ : EAQ;
      const float* hsrc = half ? hc : h_atom;
      int Msrc = half ? NQT : NAT;

      k_pre<4><<<Msrc/64, 256, 0, stream>>>(hsrc, nullptr, nullptr,
          W1ap + (size_t)j*32768, Psrc);
      k_pre<8><<<NQT/64, 256, 0, stream>>>(hc, temb, mb1 + (size_t)j*256,
          W1bcp + (size_t)j*65536, Ptgt);

      hipMemsetAsync(agg, 0, (size_t)NQT*128*sizeof(float), stream);
      k_edge<<<E/32, 256, 0, stream>>>(Psrc, Ptgt,
          half ? x_t : atom_pos, x_t, dsc,
          mW1 + (size_t)j*385*256 + 65536,
          W2p + (size_t)j*32768, mb2 + (size_t)j*128,
          W3p + (size_t)j*8192,  cb1 + (size_t)j*64,
          cW2 + (size_t)j*64,    cb2 + (size_t)j,
          agg, vel);
      k_node<<<NQT/32, 256, 0, stream>>>(hc, agg,
          nW1p + (size_t)j*32768, nb1 + (size_t)j*128,
          nW2p + (size_t)j*16384, nb2 + (size_t)j*128,
          lng + (size_t)j*128,    lnb + (size_t)j*128, hn);
      float* tmp = hc; hc = hn; hn = tmp;
    }
  }
  k_out<<<NQT, 128, 0, stream>>>(hc, vel, voW1, vob1, voW2, vob2, out);
}